// Round 14
// baseline (680.031 us; speedup 1.0000x reference)
//
#include <hip/hip_runtime.h>
#include <math.h>

// ---------------------------------------------------------------------------
// CapsNet forward.  conv1 as MFMA implicit-GEMM (bf16x2) -> conv2 implicit-
// GEMM MFMA 16x16x32 (bf16x2, M=64, 4 waves, A-only LDS 3-buf swizzled,
// counted vmcnt, B streamed to regs).  conv2 split-K:
//   8-way by 32-ci slices, slice pinned to XCD (cig = blk&7) so each XCD's
//   B working set (2.65MB) is L2-resident  [needs 202MB ws]
//   fallback: round-7 proven 3-way ky split  [needs 155MB ws]
// -> squash -> routing (s_pass inline softmax) -> finalize -> decoder MLP.
// ---------------------------------------------------------------------------

typedef __attribute__((ext_vector_type(8))) short short8;
typedef __attribute__((ext_vector_type(4))) float f32x4;

__device__ __forceinline__ unsigned short f2bf(float x) {
  unsigned int u = __float_as_uint(x);
  unsigned int r = (u + 0x7fffu + ((u >> 16) & 1u)) >> 16;
  return (unsigned short)r;
}
__device__ __forceinline__ float bf2f(unsigned short h) {
  return __uint_as_float(((unsigned int)h) << 16);
}
__device__ __forceinline__ void gload16(const void* g, void* l) {
  __builtin_amdgcn_global_load_lds(
      (const __attribute__((address_space(1))) unsigned int*)g,
      (__attribute__((address_space(3))) unsigned int*)l, 16, 0, 0);
}
__device__ __forceinline__ float dot8(const float* w, float4 a, float4 b) {
  return w[0]*a.x + w[1]*a.y + w[2]*a.z + w[3]*a.w +
         w[4]*b.x + w[5]*b.y + w[6]*b.z + w[7]*b.w;
}

// ===== w1 prep: w1[256co][81] fp32 -> w1t[co][96] bf16 hi/lo (k>=81 -> 0) ===
__global__ void w1prep(const float* __restrict__ w1,
                       unsigned short* __restrict__ w1th,
                       unsigned short* __restrict__ w1tl)
{
  const int k  = blockIdx.x;       // 0..95
  const int co = threadIdx.x;      // 0..255
  float x = (k < 81) ? w1[co * 81 + k] : 0.f;
  unsigned short h = f2bf(x);
  w1th[co * 96 + k] = h;
  w1tl[co * 96 + k] = f2bf(x - bf2f(h));
}

// ===== conv1 MFMA: [256,1,28,28] -> relu -> bf16x2 CL [256*400][256] ========
__global__ __launch_bounds__(256) void conv1_mfma(
    const float* __restrict__ data, const unsigned short* __restrict__ w1th,
    const unsigned short* __restrict__ w1tl, const float* __restrict__ b1,
    unsigned short* __restrict__ xh, unsigned short* __restrict__ xl)
{
  __shared__ float img[1344];          // [0,784) image, [784,1344) zeros
  __shared__ int offt[96];             // k -> dy*28+dx ; k>=81 -> 784
  const int t   = threadIdx.x;
  const int b   = blockIdx.x >> 1;
  const int coh = blockIdx.x & 1;
  const int lane = t & 63, w = t >> 6;
  const int l15 = lane & 15, l4 = lane >> 4;

  for (int i = t; i < 1344; i += 256) img[i] = (i < 784) ? data[b * 784 + i] : 0.f;
  if (t < 96) offt[t] = (t < 81) ? ((t / 9) * 28 + (t % 9)) : 784;
  __syncthreads();

  short8 bh[3][2], bl[3][2];
  #pragma unroll
  for (int ks = 0; ks < 3; ks++)
    #pragma unroll
    for (int nf = 0; nf < 2; nf++) {
      const int co = coh * 128 + w * 32 + nf * 16 + l15;
      bh[ks][nf] = *(const short8*)(w1th + co * 96 + ks * 32 + l4 * 8);
      bl[ks][nf] = *(const short8*)(w1tl + co * 96 + ks * 32 + l4 * 8);
    }
  int koff[3][8];
  #pragma unroll
  for (int ks = 0; ks < 3; ks++)
    #pragma unroll
    for (int j = 0; j < 8; j++)
      koff[ks][j] = offt[ks * 32 + l4 * 8 + j];
  float bv[2];
  bv[0] = b1[coh * 128 + w * 32 + l15];
  bv[1] = b1[coh * 128 + w * 32 + 16 + l15];

  #pragma unroll 1
  for (int mf = 0; mf < 25; mf++) {
    const int p  = mf * 16 + l15;
    const int oy = p / 20, ox = p - oy * 20;
    const int base = oy * 28 + ox;
    f32x4 acc[2];
    acc[0] = (f32x4){0.f, 0.f, 0.f, 0.f};
    acc[1] = (f32x4){0.f, 0.f, 0.f, 0.f};
    #pragma unroll
    for (int ks = 0; ks < 3; ks++) {
      short8 ah, al;
      #pragma unroll
      for (int j = 0; j < 8; j++) {
        float a = img[base + koff[ks][j]];
        unsigned short h = f2bf(a);
        ah[j] = (short)h;
        al[j] = (short)f2bf(a - bf2f(h));
      }
      #pragma unroll
      for (int nf = 0; nf < 2; nf++) {
        f32x4 a4 = acc[nf];
        a4 = __builtin_amdgcn_mfma_f32_16x16x32_bf16(ah, bh[ks][nf], a4, 0, 0, 0);
        a4 = __builtin_amdgcn_mfma_f32_16x16x32_bf16(al, bh[ks][nf], a4, 0, 0, 0);
        a4 = __builtin_amdgcn_mfma_f32_16x16x32_bf16(ah, bl[ks][nf], a4, 0, 0, 0);
        acc[nf] = a4;
      }
    }
    #pragma unroll
    for (int nf = 0; nf < 2; nf++) {
      const int co = coh * 128 + w * 32 + nf * 16 + l15;
      #pragma unroll
      for (int reg = 0; reg < 4; reg++) {
        const int p2 = mf * 16 + l4 * 4 + reg;
        float v = fmaxf(acc[nf][reg] + bv[nf], 0.f);
        unsigned short h = f2bf(v);
        const int pix = b * 400 + p2;
        xh[pix * 256 + co] = h;
        xl[pix * 256 + co] = f2bf(v - bf2f(h));
      }
    }
  }
}

// == conv2 weight prep: pw[co][ci][81] fp32 -> wq[k][cc][co][32] bf16 hi/lo ==
__global__ void wprep(const float* __restrict__ pw, unsigned short* __restrict__ wh,
                      unsigned short* __restrict__ wl)
{
  const int co = blockIdx.x;
  const int t  = threadIdx.x;                 // t = ci
  __shared__ float slab[20736];               // [ci][81] for this co
  for (int i = t; i < 20736; i += 256) slab[i] = pw[co * 20736 + i];
  __syncthreads();
  const int cc = t >> 5, ci5 = t & 31;
  for (int k = 0; k < 81; k++) {
    float x = slab[t * 81 + k];
    unsigned short h = f2bf(x);
    int dst = ((k * 8 + cc) * 256 + co) * 32 + ci5;
    wh[dst] = h;
    wl[dst] = f2bf(x - bf2f(h));
  }
}

// ===== conv2 8-way: block 64pix x 256co, 4 waves; split-K by 32-ci slice ====
// grid 1152 = 144 mt x 8 cig (cig = blk&7 -> pinned to XCD blk%8; per-XCD B
// slab 2.65MB fits the 4MB L2).  81 k-pos steps of 32 ci; LDS 24KB = 3x8KB.
// Swizzle: granule g at slot g^((g>>3)&7) (involution), inverse on the
// per-lane GLOBAL source address; counted vmcnt(10) = 8 B(s) + 2 A(s+1).
__global__ __launch_bounds__(256) void conv2_mfma8(
    const unsigned short* __restrict__ xh, const unsigned short* __restrict__ xl,
    const unsigned short* __restrict__ wh, const unsigned short* __restrict__ wl,
    float* __restrict__ part)
{
  __shared__ char lds[24576];
  const int t   = threadIdx.x;
  const int blk = blockIdx.x;
  const int cig = blk & 7;               // 32-ci slice, pinned to XCD
  const int mt  = blk >> 3;              // 0..143
  const int m0  = mt * 64;
  const int lane = t & 63;
  const int w    = t >> 6;
  const int l15  = lane & 15, l4 = lane >> 4;

  // staging: slot t holds granule g0 = t ^ ((t>>3)&7); row = g0>>2, ch = g0&3
  const int g0  = t ^ ((t >> 3) & 7);
  const int ar  = g0 >> 2;               // 0..63
  const int ach = g0 & 3;                // 8-ci chunk within 32-ci window
  auto pixbase = [&](int pix) {
    int ab = pix / 36; int sp = pix - ab * 36;
    int oy = sp / 6;   int ox = sp - oy * 6;
    return ((ab * 20 + 2 * oy) * 20 + 2 * ox) * 256;
  };
  const int abase = pixbase(m0 + ar) + cig * 32 + ach * 8;

  const int bofs = (w * 64 + l15) * 32 + l4 * 8;   // into one (k,cc32) slab

  f32x4 acc[4][4];
  #pragma unroll
  for (int i = 0; i < 4; i++)
    #pragma unroll
    for (int j = 0; j < 4; j++) acc[i][j] = (f32x4){0.f, 0.f, 0.f, 0.f};

  auto stageA = [&](int buf, int xy) {             // xy = (ky*20+kx)*256
    char* base = lds + buf * 8192;
    gload16(xh + abase + xy, base + t * 16);
    gload16(xl + abase + xy, base + 4096 + t * 16);
  };

  stageA(0, 0);
  #pragma unroll 1
  for (int s = 0; s < 81; ++s) {
    // B for CURRENT step: 8 x 16B register loads (L2-resident slab)
    const int slab = (s * 8 + cig) * 8192 + bofs;
    short8 b_h[4], b_l[4];
    #pragma unroll
    for (int nf = 0; nf < 4; nf++) {
      b_h[nf] = *(const short8*)(wh + slab + nf * 512);
      b_l[nf] = *(const short8*)(wl + slab + nf * 512);
    }
    if (s < 80) {
      const int ns = s + 1;
      const int ky = ns / 9, kx = ns - ky * 9;
      stageA(ns % 3, (ky * 20 + kx) * 256);
      asm volatile("s_waitcnt vmcnt(10)" ::: "memory");  // A(s) landed; B(s)+A(s+1) in flight
    } else {
      asm volatile("s_waitcnt vmcnt(8)" ::: "memory");   // A(s) landed; B(s) in flight
    }
    asm volatile("s_barrier" ::: "memory");

    char* base = lds + (s % 3) * 8192;
    short8 a_h[4], a_l[4];
    #pragma unroll
    for (int mf = 0; mf < 4; mf++) {
      const int g = (mf * 16 + l15) * 4 + l4;
      const int off = (g ^ ((g >> 3) & 7)) << 4;
      a_h[mf] = *(const short8*)(base + off);
      a_l[mf] = *(const short8*)(base + 4096 + off);
    }
    __builtin_amdgcn_s_setprio(1);
    #pragma unroll
    for (int nf = 0; nf < 4; nf++)
      #pragma unroll
      for (int mf = 0; mf < 4; mf++) {
        f32x4 a = acc[mf][nf];
        a = __builtin_amdgcn_mfma_f32_16x16x32_bf16(a_h[mf], b_h[nf], a, 0, 0, 0);
        a = __builtin_amdgcn_mfma_f32_16x16x32_bf16(a_l[mf], b_h[nf], a, 0, 0, 0);
        a = __builtin_amdgcn_mfma_f32_16x16x32_bf16(a_h[mf], b_l[nf], a, 0, 0, 0);
        acc[mf][nf] = a;
      }
    __builtin_amdgcn_s_setprio(0);
  }

  // epilogue: C[pix][co]; 16x16 C/D: col=lane&15, row=(lane>>4)*4+reg
  float* pout = part + cig * 2359296;
  #pragma unroll
  for (int mf = 0; mf < 4; mf++)
    #pragma unroll
    for (int nf = 0; nf < 4; nf++) {
      const int co = w * 64 + nf * 16 + l15;
      #pragma unroll
      for (int reg = 0; reg < 4; reg++) {
        const int pix = m0 + mf * 16 + l4 * 4 + reg;
        const int b  = pix / 36;
        const int sp = pix - b * 36;
        pout[b * 9216 + co * 36 + sp] = acc[mf][nf][reg];
      }
    }
}

// ===== conv2 fallback: round-7/13 proven 3-way ky split (needs 155MB ws) ====
__global__ __launch_bounds__(256) void conv2_mfma(
    const unsigned short* __restrict__ xh, const unsigned short* __restrict__ xl,
    const unsigned short* __restrict__ wh, const unsigned short* __restrict__ wl,
    float* __restrict__ part)
{
  __shared__ char lds[49152];
  const int t   = threadIdx.x;
  const int blk = blockIdx.x;
  const int mt  = blk % 144;
  const int kg  = blk / 144;
  const int m0  = mt * 64;
  const int lane = t & 63;
  const int w    = t >> 6;
  const int l15  = lane & 15, l4 = lane >> 4;

  const int g0  = t ^ ((t >> 3) & 7);
  const int ar0 = g0 >> 3;
  const int ach = g0 & 7;
  auto pixbase = [&](int pix) {
    int ab = pix / 36; int sp = pix - ab * 36;
    int oy = sp / 6;   int ox = sp - oy * 6;
    return ((ab * 20 + 2 * oy) * 20 + 2 * ox) * 256;
  };
  const int abase0 = pixbase(m0 + ar0) + ach * 8;
  const int abase1 = pixbase(m0 + ar0 + 32) + ach * 8;

  const int bofs = (w * 64 + l15) * 32 + l4 * 8;

  f32x4 acc[4][4];
  #pragma unroll
  for (int i = 0; i < 4; i++)
    #pragma unroll
    for (int j = 0; j < 4; j++) acc[i][j] = (f32x4){0.f, 0.f, 0.f, 0.f};

  const int ky0 = kg * 3;

  auto stageA = [&](int buf, int xy, int ci0) {
    char* base = lds + buf * 16384;
    gload16(xh + abase0 + xy + ci0, base + t * 16);
    gload16(xh + abase1 + xy + ci0, base + 4096  + t * 16);
    gload16(xl + abase0 + xy + ci0, base + 8192  + t * 16);
    gload16(xl + abase1 + xy + ci0, base + 12288 + t * 16);
  };

  stageA(0, ky0 * 20 * 256, 0);
  int kyc = ky0, kxc = 0, cc2 = 0;
  #pragma unroll 1
  for (int s = 0; s < 108; ++s) {
    const int kkc = (kyc * 9 + kxc) * 8 + cc2 * 2;
    short8 b_h[4][2], b_l[4][2];
    #pragma unroll
    for (int ks = 0; ks < 2; ks++) {
      const unsigned short* bhp = wh + (kkc + ks) * 8192 + bofs;
      const unsigned short* blp = wl + (kkc + ks) * 8192 + bofs;
      #pragma unroll
      for (int nf = 0; nf < 4; nf++) {
        b_h[nf][ks] = *(const short8*)(bhp + nf * 512);
        b_l[nf][ks] = *(const short8*)(blp + nf * 512);
      }
    }
    cc2++; if (cc2 == 4) { cc2 = 0; kxc++; if (kxc == 9) { kxc = 0; kyc++; } }
    if (s < 107) {
      stageA((s + 1) % 3, (kyc * 20 + kxc) * 256, cc2 * 64);
      asm volatile("s_waitcnt vmcnt(20)" ::: "memory");
    } else {
      asm volatile("s_waitcnt vmcnt(16)" ::: "memory");
    }
    asm volatile("s_barrier" ::: "memory");

    char* base = lds + (s % 3) * 16384;
    #pragma unroll
    for (int ks = 0; ks < 2; ks++) {
      short8 a_h[4], a_l[4];
      #pragma unroll
      for (int mf = 0; mf < 4; mf++) {
        const int row = mf * 16 + l15;
        const int off = ((row * 8 + ks * 4 + l4) ^ (l15 & 7)) << 4;
        a_h[mf] = *(const short8*)(base + off);
        a_l[mf] = *(const short8*)(base + 8192 + off);
      }
      __builtin_amdgcn_s_setprio(1);
      #pragma unroll
      for (int nf = 0; nf < 4; nf++)
        #pragma unroll
        for (int mf = 0; mf < 4; mf++) {
          f32x4 a = acc[mf][nf];
          a = __builtin_amdgcn_mfma_f32_16x16x32_bf16(a_h[mf], b_h[nf][ks], a, 0, 0, 0);
          a = __builtin_amdgcn_mfma_f32_16x16x32_bf16(a_l[mf], b_h[nf][ks], a, 0, 0, 0);
          a = __builtin_amdgcn_mfma_f32_16x16x32_bf16(a_h[mf], b_l[nf][ks], a, 0, 0, 0);
          acc[mf][nf] = a;
        }
      __builtin_amdgcn_s_setprio(0);
    }
  }

  float* pout = part + kg * 2359296;
  #pragma unroll
  for (int mf = 0; mf < 4; mf++)
    #pragma unroll
    for (int nf = 0; nf < 4; nf++) {
      const int co = w * 64 + nf * 16 + l15;
      #pragma unroll
      for (int reg = 0; reg < 4; reg++) {
        const int pix = m0 + mf * 16 + l4 * 4 + reg;
        const int b  = pix / 36;
        const int sp = pix - b * 36;
        pout[b * 9216 + co * 36 + sp] = acc[mf][nf][reg];
      }
    }
}

// ======= combine np split-K partials + bias, squash(8); emit u_T only =======
__global__ void combine_squash(const float* __restrict__ part,
                               const float* __restrict__ pb,
                               float* __restrict__ uT, int np)
{
  const int id = blockIdx.x * 256 + threadIdx.x;  // 0..294911
  const int b = id / 1152;
  const int r = id % 1152;
  const float* p0 = part + b * 9216 + r * 8;
  float v[8];
  #pragma unroll
  for (int i = 0; i < 8; i++) v[i] = p0[i];
  #pragma unroll 1
  for (int p = 1; p < np; p++)
    #pragma unroll
    for (int i = 0; i < 8; i++) v[i] += p0[p * 2359296 + i];
  #pragma unroll
  for (int i = 0; i < 8; i++) v[i] += pb[(r * 8 + i) / 36];
  float sq = 0.f;
  #pragma unroll
  for (int i = 0; i < 8; i++) sq += v[i] * v[i];
  float scale = sq / ((1.f + sq) * sqrtf(sq));
  #pragma unroll
  for (int i = 0; i < 8; i++) uT[(r * 256 + b) * 8 + i] = v[i] * scale;
}

// ===== s partials: grid 640 = 10 c x 64 r-chunks(18); block 256 (thread=b) ==
__global__ __launch_bounds__(256) void s_pass(
    const float* __restrict__ uT, const float* __restrict__ Wdc,
    const float* __restrict__ bij, float* __restrict__ spart, int uniform)
{
  const int c  = blockIdx.x % 10;
  const int q  = blockIdx.x / 10;          // 0..63
  const int r0 = q * 18;
  const int t  = threadIdx.x;
  __shared__ float wsm[18 * 128];          // 9216 B
  __shared__ float cw[18];
  __shared__ float red[8];

  #pragma unroll
  for (int k = 0; k < 9; k++) {
    int idx = t + k * 256;                 // < 2304
    int r = idx >> 7, i = idx & 127;
    wsm[idx] = Wdc[((r0 + r) * 10 + c) * 128 + i];
  }
  if (uniform) {
    if (t < 18) cw[t] = 1.f / 1152.f;
  } else {
    float bv[5]; float m = -1e30f;
    #pragma unroll
    for (int rr = 0; rr < 5; rr++) {
      int r = t + rr * 256;
      bv[rr] = (r < 1152) ? bij[c * 1152 + r] : -1e30f;
      m = fmaxf(m, bv[rr]);
    }
    #pragma unroll
    for (int off = 32; off; off >>= 1) m = fmaxf(m, __shfl_down(m, off, 64));
    if ((t & 63) == 0) red[t >> 6] = m;
    __syncthreads();
    m = fmaxf(fmaxf(red[0], red[1]), fmaxf(red[2], red[3]));
    float ssum = 0.f;
    #pragma unroll
    for (int rr = 0; rr < 5; rr++)
      ssum += (t + rr * 256 < 1152) ? expf(bv[rr] - m) : 0.f;
    #pragma unroll
    for (int off = 32; off; off >>= 1) ssum += __shfl_down(ssum, off, 64);
    if ((t & 63) == 0) red[4 + (t >> 6)] = ssum;
    __syncthreads();
    float inv = 1.f / (red[4] + red[5] + red[6] + red[7]);
    if (t < 18) cw[t] = expf(bij[c * 1152 + r0 + t] - m) * inv;
  }
  __syncthreads();

  const float4* up = (const float4*)(uT + (r0 * 256 + t) * 8);
  float acc[16];
  #pragma unroll
  for (int o = 0; o < 16; o++) acc[o] = 0.f;
  #pragma unroll 1
  for (int r = 0; r < 18; r++) {
    float4 x0 = up[r * 512], x1 = up[r * 512 + 1];
    float cwr = cw[r];
    const float* wr = &wsm[r * 128];
    #pragma unroll
    for (int o = 0; o < 16; o++) {
      const float4 wa = *(const float4*)(wr + o * 8);
      const float4 wb = *(const float4*)(wr + o * 8 + 4);
      acc[o] += cwr * (wa.x*x0.x + wa.y*x0.y + wa.z*x0.z + wa.w*x0.w
                     + wb.x*x1.x + wb.y*x1.y + wb.z*x1.z + wb.w*x1.w);
    }
  }
  float* op = spart + q * 40960 + (t * 10 + c) * 16;
  #pragma unroll
  for (int o = 0; o < 16; o++) op[o] = acc[o];
}

// ===== fused: sum 64 r-chunk partials; non-final: squash -> vT; final: sbuf =
template <int FINAL>
__global__ void reduce_squash(const float* __restrict__ spart, float* __restrict__ outb)
{
  const int id = blockIdx.x * 256 + threadIdx.x;   // < 40960; id=(b*10+c)*16+o
  float a = 0.f;
  #pragma unroll 8
  for (int q = 0; q < 64; q++) a += spart[q * 40960 + id];
  if (FINAL) { outb[id] = a; return; }
  float sq = a * a;
  #pragma unroll
  for (int off = 8; off; off >>= 1) sq += __shfl_xor(sq, off, 16);
  float scale = sq / ((1.f + sq) * sqrtf(sq));
  const int bc = id >> 4, o = id & 15;
  const int b = bc / 10, c = bc - b * 10;
  outb[(c * 256 + b) * 16 + o] = a * scale;
}

// == a[r,c] = (1/B) sum_{b,o} dot(W[r,c,o],u[b,r]) * v[b,c,o]; bij (+)= a ====
__global__ __launch_bounds__(256) void a_pass(
    const float* __restrict__ uT, const float* __restrict__ W,
    const float* __restrict__ vT, float* __restrict__ bij, int assign)
{
  const int r = blockIdx.x;
  const int t = threadIdx.x;
  __shared__ float wsl[1280];
  __shared__ float lred[4][10];
  for (int i = t; i < 1280; i += 256) wsl[i] = W[r * 1280 + i];
  __syncthreads();
  const float4* up = (const float4*)(uT + (r * 256 + t) * 8);
  float4 ua = up[0], ub = up[1];
  const int lane = t & 63, wid = t >> 6;
  #pragma unroll 1
  for (int c = 0; c < 10; c++) {
    const float* wc = &wsl[c * 128];
    const float4* vp = (const float4*)(vT + (c * 256 + t) * 16);
    float p = 0.f;
    #pragma unroll
    for (int q = 0; q < 4; q++) {
      float4 vq = vp[q];
      p += dot8(wc + (q * 4 + 0) * 8, ua, ub) * vq.x;
      p += dot8(wc + (q * 4 + 1) * 8, ua, ub) * vq.y;
      p += dot8(wc + (q * 4 + 2) * 8, ua, ub) * vq.z;
      p += dot8(wc + (q * 4 + 3) * 8, ua, ub) * vq.w;
    }
    for (int off = 32; off; off >>= 1) p += __shfl_down(p, off, 64);
    if (lane == 0) lred[wid][c] = p;
  }
  __syncthreads();
  if (t < 10) {
    float a = (lred[0][t] + lred[1][t] + lred[2][t] + lred[3][t]) * (1.f / 256.f);
    float o = assign ? 0.f : bij[t * 1152 + r];
    bij[t * 1152 + r] = o + a;
  }
}

// == finalize: squash(final) -> outp; batch softmax; argmax mask; t vector ===
__global__ __launch_bounds__(256) void finalize(
    const float* __restrict__ sbuf, float* __restrict__ outp,
    float* __restrict__ maskedo, float* __restrict__ tbuf)
{
  const int b = threadIdx.x;
  __shared__ float nsm[256][10];
  __shared__ float red[8];
  #pragma unroll 1
  for (int c = 0; c < 10; c++) {
    const float4* sp = (const float4*)(sbuf + (b * 10 + c) * 16);
    float4 q0 = sp[0], q1 = sp[1], q2 = sp[2], q3 = sp[3];
    float sq = q0.x*q0.x+q0.y*q0.y+q0.z*q0.z+q0.w*q0.w
             + q1.x*q1.x+q1.y*q1.y+q1.z*q1.z+q1.w*q1.w
             + q2.x*q2.x+q2.y*q2.y+q2.z*q2.z+q2.w*q2.w
             + q3.x*q3.x+q3.y*q3.y+q3.z*q3.z+q3.w*q3.w;
    float scale = sq / ((1.f + sq) * sqrtf(sq));
    float4* op = (float4*)(outp + (b * 10 + c) * 16);
    op[0] = make_float4(q0.x*scale, q0.y*scale, q0.z*scale, q0.w*scale);
    op[1] = make_float4(q1.x*scale, q1.y*scale, q1.z*scale, q1.w*scale);
    op[2] = make_float4(q2.x*scale, q2.y*scale, q2.z*scale, q2.w*scale);
    op[3] = make_float4(q3.x*scale, q3.y*scale, q3.z*scale, q3.w*scale);
    nsm[b][c] = sq / (1.f + sq);          // = ||squash(s)||
  }
  __syncthreads();
  float sc[10];
  #pragma unroll
  for (int c = 0; c < 10; c++) {
    float x = nsm[b][c];
    float m = x;
    #pragma unroll
    for (int off = 32; off; off >>= 1) m = fmaxf(m, __shfl_down(m, off, 64));
    if ((b & 63) == 0) red[b >> 6] = m;
    __syncthreads();
    m = fmaxf(fmaxf(red[0], red[1]), fmaxf(red[2], red[3]));
    float e = expf(x - m), ss = e;
    #pragma unroll
    for (int off = 32; off; off >>= 1) ss += __shfl_down(ss, off, 64);
    if ((b & 63) == 0) red[4 + (b >> 6)] = ss;
    __syncthreads();
    sc[c] = e / (red[4] + red[5] + red[6] + red[7]);
    __syncthreads();
  }
  int idx = 0; float best = sc[0];
  #pragma unroll
  for (int c = 1; c < 10; c++) if (sc[c] > best) { best = sc[c]; idx = c; }
  #pragma unroll
  for (int c = 0; c < 10; c++) {
    float msk = (c == idx) ? 1.f : 0.f;
    maskedo[b * 10 + c] = msk;
    const float4* op = (const float4*)(outp + (b * 10 + c) * 16);
    float4* tp = (float4*)(tbuf + b * 160 + c * 16);
    #pragma unroll
    for (int qq = 0; qq < 4; qq++) {
      float4 vv = op[qq];
      tp[qq] = make_float4(vv.x * msk, vv.y * msk, vv.z * msk, vv.w * msk);
    }
  }
}

// ==================== small GEMM: C = act(A[M,K] @ B[K,N] + bias) ===========
template <int ACT>
__global__ __launch_bounds__(256) void gemm_act(
    const float* __restrict__ A, const float* __restrict__ B,
    const float* __restrict__ bias, float* __restrict__ C, int M, int N, int K)
{
  __shared__ float As[64][17];
  __shared__ float Bs[16][64];
  const int t = threadIdx.x;
  const int tx = t & 15, ty = t >> 4;
  const int m0 = blockIdx.y * 64, n0 = blockIdx.x * 64;
  float acc[4][4] = {};
  for (int kb = 0; kb < K; kb += 16) {
    {
      int row = t >> 2, c4 = (t & 3) * 4;
      float4 av = *(const float4*)(A + (m0 + row) * K + kb + c4);
      As[row][c4+0]=av.x; As[row][c4+1]=av.y; As[row][c4+2]=av.z; As[row][c4+3]=av.w;
    }
    {
      int row = t >> 4, c4 = (t & 15) * 4;
      float4 bv = make_float4(0.f, 0.f, 0.f, 0.f);
      if (n0 + c4 < N) bv = *(const float4*)(B + (kb + row) * N + n0 + c4);
      Bs[row][c4+0]=bv.x; Bs[row][c4+1]=bv.y; Bs[row][c4+2]=bv.z; Bs[row][c4+3]=bv.w;
    }
    __syncthreads();
    #pragma unroll
    for (int kk = 0; kk < 16; kk++) {
      float a_[4], b_[4];
      #pragma unroll
      for (int i = 0; i < 4; i++) a_[i] = As[ty * 4 + i][kk];
      #pragma unroll
      for (int j = 0; j < 4; j++) b_[j] = Bs[kk][tx * 4 + j];
      #pragma unroll
      for (int i = 0; i < 4; i++)
        for (int j = 0; j < 4; j++)
          acc[i][j] = fmaf(a_[i], b_[j], acc[i][j]);
    }
    __syncthreads();
  }
  #pragma unroll
  for (int i = 0; i < 4; i++) {
    int row = m0 + ty * 4 + i;
    #pragma unroll
    for (int j = 0; j < 4; j++) {
      int col = n0 + tx * 4 + j;
      if (col < N) {
        float val = acc[i][j] + bias[col];
        if (ACT == 0) val = val > 0.f ? val : 0.f;
        else          val = 1.f / (1.f + expf(-val));
        C[row * N + col] = val;
      }
    }
  }
}

// ===========================================================================
extern "C" void kernel_launch(void* const* d_in, const int* in_sizes, int n_in,
                              void* d_out, int out_size, void* d_ws, size_t ws_size,
                              hipStream_t stream)
{
  const float* data = (const float*)d_in[0];
  const float* w1   = (const float*)d_in[1];
  const float* b1   = (const float*)d_in[2];
  const float* pw   = (const float*)d_in[3];
  const float* pb   = (const float*)d_in[4];
  const float* Wdc  = (const float*)d_in[5];
  const float* dw1  = (const float*)d_in[6];
  const float* db1  = (const float*)d_in[7];
  const float* dw2  = (const float*)d_in[8];
  const float* db2  = (const float*)d_in[9];
  const float* dw3  = (const float*)d_in[10];
  const float* db3  = (const float*)d_in[11];

  float* out     = (float*)d_out;
  float* outp    = out;              // [256][10][16][1]
  float* recon   = out + 40960;      // [256][784]
  float* maskedo = out + 241664;     // [256][10]

  char* wsb = (char*)d_ws;
  // big section (conv phase)
  unsigned short* x1h = (unsigned short*)(wsb);               // 52,428,800 B
  unsigned short* x1l = (unsigned short*)(wsb + 52428800);    // 52,428,800
  unsigned short* wbh = (unsigned short*)(wsb + 104857600);   // 10,616,832
  unsigned short* wbl = (unsigned short*)(wsb + 115474432);   // 10,616,832
  float*  part = (float*)(wsb + 126091264);                   // 3 or 8 x 9,437,184
  unsigned short* w1th = (unsigned short*)(wsb + 126066688 - 196608);  // see below
  // w1t buffers: place in the tail of the wbl gap region? keep simple:
  // put them after part's max extent is unknown -> carve from the x1l tail is
  // unsafe.  Use fixed slots before part only when fallback (3 parts) is
  // active; for the 8-way path ws must fit 202MB + 96KB.
  const size_t need8 = 126091264ull + 8ull * 9437184ull + 196608ull;
  const int use8 = (ws_size >= need8);
  const size_t w1off = use8 ? (126091264ull + 8ull * 9437184ull)
                            : (126091264ull + 3ull * 9437184ull);
  w1th = (unsigned short*)(wsb + w1off);                      //     49,152
  unsigned short* w1tl = (unsigned short*)(wsb + w1off + 98304);
  // overlay section (x1h region is dead after conv2)
  float* uT   = (float*)(wsb);                                //  9,437,184
  float* vT   = (float*)(wsb + 9437184);                      //    163,840
  float* bij  = (float*)(wsb + 9601024);                      //     46,080
  float* sbuf = (float*)(wsb + 9647104);                      //    163,840
  float* spart= (float*)(wsb + 9810944);                      // 10,485,760
  float* tbuf = (float*)(wsb + 20296704);                     //    163,840
  float* h1   = (float*)(wsb + 20460544);                     //    524,288
  float* h2   = (float*)(wsb + 20984832);                     //  1,048,576

  w1prep<<<96, 256, 0, stream>>>(w1, w1th, w1tl);
  conv1_mfma<<<512, 256, 0, stream>>>(data, w1th, w1tl, b1, x1h, x1l);
  wprep<<<256, 256, 0, stream>>>(pw, wbh, wbl);
  if (use8) {
    conv2_mfma8<<<1152, 256, 0, stream>>>(x1h, x1l, wbh, wbl, part);
    combine_squash<<<1152, 256, 0, stream>>>(part, pb, uT, 8);
  } else {
    conv2_mfma<<<432, 256, 0, stream>>>(x1h, x1l, wbh, wbl, part);
    combine_squash<<<1152, 256, 0, stream>>>(part, pb, uT, 3);
  }

  // routing iteration 0 (b_ij = 0 -> uniform c); b_ij assigned, not added
  s_pass<<<640, 256, 0, stream>>>(uT, Wdc, bij, spart, 1);
  reduce_squash<0><<<160, 256, 0, stream>>>(spart, vT);
  a_pass<<<1152, 256, 0, stream>>>(uT, Wdc, vT, bij, 1);
  // iteration 1
  s_pass<<<640, 256, 0, stream>>>(uT, Wdc, bij, spart, 0);
  reduce_squash<0><<<160, 256, 0, stream>>>(spart, vT);
  a_pass<<<1152, 256, 0, stream>>>(uT, Wdc, vT, bij, 0);
  // iteration 2 (final) + fused decoder head
  s_pass<<<640, 256, 0, stream>>>(uT, Wdc, bij, spart, 0);
  reduce_squash<1><<<160, 256, 0, stream>>>(spart, sbuf);
  finalize<<<1, 256, 0, stream>>>(sbuf, outp, maskedo, tbuf);

  gemm_act<0><<<dim3(8, 4),  256, 0, stream>>>(tbuf, dw1, db1, h1,    256, 512,  160);
  gemm_act<0><<<dim3(16, 4), 256, 0, stream>>>(h1,   dw2, db2, h2,    256, 1024, 512);
  gemm_act<1><<<dim3(13, 4), 256, 0, stream>>>(h2,   dw3, db3, recon, 256, 784,  1024);
}

// Round 15
// 649.039 us; speedup vs baseline: 1.0478x; 1.0478x over previous
//
#include <hip/hip_runtime.h>
#include <math.h>

// ---------------------------------------------------------------------------
// CapsNet forward.  conv1 as MFMA implicit-GEMM (bf16x2, image in LDS,
// on-the-fly im2col) -> conv2 implicit-GEMM MFMA 16x16x32 (bf16x2, M=64,
// 4 waves, A-only LDS 3x16KB swizzled zero-conflict, counted vmcnt, B
// streamed L2/L3->regs, 3-way ky split-K) [round-13 proven, 649us total] ->
// squash -> routing (s_pass inline softmax) -> finalize -> decoder MLP.
// ---------------------------------------------------------------------------

typedef __attribute__((ext_vector_type(8))) short short8;
typedef __attribute__((ext_vector_type(4))) float f32x4;

__device__ __forceinline__ unsigned short f2bf(float x) {
  unsigned int u = __float_as_uint(x);
  unsigned int r = (u + 0x7fffu + ((u >> 16) & 1u)) >> 16;
  return (unsigned short)r;
}
__device__ __forceinline__ float bf2f(unsigned short h) {
  return __uint_as_float(((unsigned int)h) << 16);
}
__device__ __forceinline__ void gload16(const void* g, void* l) {
  __builtin_amdgcn_global_load_lds(
      (const __attribute__((address_space(1))) unsigned int*)g,
      (__attribute__((address_space(3))) unsigned int*)l, 16, 0, 0);
}
__device__ __forceinline__ float dot8(const float* w, float4 a, float4 b) {
  return w[0]*a.x + w[1]*a.y + w[2]*a.z + w[3]*a.w +
         w[4]*b.x + w[5]*b.y + w[6]*b.z + w[7]*b.w;
}

// ===== w1 prep: w1[256co][81] fp32 -> w1t[co][96] bf16 hi/lo (k>=81 -> 0) ===
__global__ void w1prep(const float* __restrict__ w1,
                       unsigned short* __restrict__ w1th,
                       unsigned short* __restrict__ w1tl)
{
  const int k  = blockIdx.x;       // 0..95
  const int co = threadIdx.x;      // 0..255
  float x = (k < 81) ? w1[co * 81 + k] : 0.f;
  unsigned short h = f2bf(x);
  w1th[co * 96 + k] = h;
  w1tl[co * 96 + k] = f2bf(x - bf2f(h));
}

// ===== conv1 MFMA: [256,1,28,28] -> relu -> bf16x2 CL [256*400][256] ========
// grid 512 = 256 b x 2 co-halves; 256 thr (4 waves).  A built on-the-fly from
// the 784-float image in LDS (offset table; k 81..95 reads zeroed pad x zero
// weights); B = w1t fragments, register-resident.
__global__ __launch_bounds__(256) void conv1_mfma(
    const float* __restrict__ data, const unsigned short* __restrict__ w1th,
    const unsigned short* __restrict__ w1tl, const float* __restrict__ b1,
    unsigned short* __restrict__ xh, unsigned short* __restrict__ xl)
{
  __shared__ float img[1344];          // [0,784) image, [784,1344) zeros
  __shared__ int offt[96];             // k -> dy*28+dx ; k>=81 -> 784
  const int t   = threadIdx.x;
  const int b   = blockIdx.x >> 1;
  const int coh = blockIdx.x & 1;
  const int lane = t & 63, w = t >> 6;
  const int l15 = lane & 15, l4 = lane >> 4;

  for (int i = t; i < 1344; i += 256) img[i] = (i < 784) ? data[b * 784 + i] : 0.f;
  if (t < 96) offt[t] = (t < 81) ? ((t / 9) * 28 + (t % 9)) : 784;
  __syncthreads();

  // B fragments (co = coh*128 + w*32 + nf*16 + l15 ; k = ks*32 + l4*8 + j)
  short8 bh[3][2], bl[3][2];
  #pragma unroll
  for (int ks = 0; ks < 3; ks++)
    #pragma unroll
    for (int nf = 0; nf < 2; nf++) {
      const int co = coh * 128 + w * 32 + nf * 16 + l15;
      bh[ks][nf] = *(const short8*)(w1th + co * 96 + ks * 32 + l4 * 8);
      bl[ks][nf] = *(const short8*)(w1tl + co * 96 + ks * 32 + l4 * 8);
    }
  int koff[3][8];
  #pragma unroll
  for (int ks = 0; ks < 3; ks++)
    #pragma unroll
    for (int j = 0; j < 8; j++)
      koff[ks][j] = offt[ks * 32 + l4 * 8 + j];
  float bv[2];
  bv[0] = b1[coh * 128 + w * 32 + l15];
  bv[1] = b1[coh * 128 + w * 32 + 16 + l15];

  #pragma unroll 1
  for (int mf = 0; mf < 25; mf++) {
    const int p  = mf * 16 + l15;           // A row (pixel)
    const int oy = p / 20, ox = p - oy * 20;
    const int base = oy * 28 + ox;
    f32x4 acc[2];
    acc[0] = (f32x4){0.f, 0.f, 0.f, 0.f};
    acc[1] = (f32x4){0.f, 0.f, 0.f, 0.f};
    #pragma unroll
    for (int ks = 0; ks < 3; ks++) {
      short8 ah, al;
      #pragma unroll
      for (int j = 0; j < 8; j++) {
        float a = img[base + koff[ks][j]];
        unsigned short h = f2bf(a);
        ah[j] = (short)h;
        al[j] = (short)f2bf(a - bf2f(h));
      }
      #pragma unroll
      for (int nf = 0; nf < 2; nf++) {
        f32x4 a4 = acc[nf];
        a4 = __builtin_amdgcn_mfma_f32_16x16x32_bf16(ah, bh[ks][nf], a4, 0, 0, 0);
        a4 = __builtin_amdgcn_mfma_f32_16x16x32_bf16(al, bh[ks][nf], a4, 0, 0, 0);
        a4 = __builtin_amdgcn_mfma_f32_16x16x32_bf16(ah, bl[ks][nf], a4, 0, 0, 0);
        acc[nf] = a4;
      }
    }
    // C: row = mf*16 + l4*4 + reg (pixel), col = co(l15); bias+relu+split
    #pragma unroll
    for (int nf = 0; nf < 2; nf++) {
      const int co = coh * 128 + w * 32 + nf * 16 + l15;
      #pragma unroll
      for (int reg = 0; reg < 4; reg++) {
        const int p2 = mf * 16 + l4 * 4 + reg;
        float v = fmaxf(acc[nf][reg] + bv[nf], 0.f);
        unsigned short h = f2bf(v);
        const int pix = b * 400 + p2;
        xh[pix * 256 + co] = h;
        xl[pix * 256 + co] = f2bf(v - bf2f(h));
      }
    }
  }
}

// == conv2 weight prep: pw[co][ci][81] fp32 -> wq[k][cc][co][32] bf16 hi/lo ==
__global__ void wprep(const float* __restrict__ pw, unsigned short* __restrict__ wh,
                      unsigned short* __restrict__ wl)
{
  const int co = blockIdx.x;
  const int t  = threadIdx.x;                 // t = ci
  __shared__ float slab[20736];               // [ci][81] for this co
  for (int i = t; i < 20736; i += 256) slab[i] = pw[co * 20736 + i];
  __syncthreads();
  const int cc = t >> 5, ci5 = t & 31;
  for (int k = 0; k < 81; k++) {
    float x = slab[t * 81 + k];
    unsigned short h = f2bf(x);
    int dst = ((k * 8 + cc) * 256 + co) * 32 + ci5;
    wh[dst] = h;
    wl[dst] = f2bf(x - bf2f(h));
  }
}

// ===== conv2 MFMA: block 64pix x 256co, 4 waves (64x64), 3-way ky split =====
// ROUND-7 PROVEN CONFIG (291us, MfmaUtil 45%, zero bank conflicts).
// grid 432; 48KB LDS (A only, 3 bufs x 16KB); 108 x 64-ci steps (cc2 0..3).
__global__ __launch_bounds__(256) void conv2_mfma(
    const unsigned short* __restrict__ xh, const unsigned short* __restrict__ xl,
    const unsigned short* __restrict__ wh, const unsigned short* __restrict__ wl,
    float* __restrict__ part)
{
  __shared__ char lds[49152];
  const int t   = threadIdx.x;
  const int blk = blockIdx.x;
  const int mt  = blk % 144;
  const int kg  = blk / 144;
  const int m0  = mt * 64;
  const int lane = t & 63;
  const int w    = t >> 6;
  const int l15  = lane & 15, l4 = lane >> 4;

  // staging: slot t holds granule g0 = t ^ ((t>>3)&7)
  const int g0  = t ^ ((t >> 3) & 7);
  const int ar0 = g0 >> 3;                 // row 0..31 (second slot: +32)
  const int ach = g0 & 7;                  // 8-ci chunk within 64-ci buffer
  auto pixbase = [&](int pix) {
    int ab = pix / 36; int sp = pix - ab * 36;
    int oy = sp / 6;   int ox = sp - oy * 6;
    return ((ab * 20 + 2 * oy) * 20 + 2 * ox) * 256;
  };
  const int abase0 = pixbase(m0 + ar0) + ach * 8;
  const int abase1 = pixbase(m0 + ar0 + 32) + ach * 8;

  const int bofs = (w * 64 + l15) * 32 + l4 * 8;   // into one (k,cc32) slab

  f32x4 acc[4][4];
  #pragma unroll
  for (int i = 0; i < 4; i++)
    #pragma unroll
    for (int j = 0; j < 4; j++) acc[i][j] = (f32x4){0.f, 0.f, 0.f, 0.f};

  const int ky0 = kg * 3;

  auto stageA = [&](int buf, int xy, int ci0) {    // xy = (ky*20+kx)*256
    char* base = lds + buf * 16384;
    gload16(xh + abase0 + xy + ci0, base + t * 16);
    gload16(xh + abase1 + xy + ci0, base + 4096  + t * 16);
    gload16(xl + abase0 + xy + ci0, base + 8192  + t * 16);
    gload16(xl + abase1 + xy + ci0, base + 12288 + t * 16);
  };

  stageA(0, ky0 * 20 * 256, 0);
  int kyc = ky0, kxc = 0, cc2 = 0;                 // current step indices
  #pragma unroll 1
  for (int s = 0; s < 108; ++s) {
    // B for CURRENT step: 16 x 16B register loads, issued earliest.
    const int kkc = (kyc * 9 + kxc) * 8 + cc2 * 2;
    short8 b_h[4][2], b_l[4][2];
    #pragma unroll
    for (int ks = 0; ks < 2; ks++) {
      const unsigned short* bhp = wh + (kkc + ks) * 8192 + bofs;
      const unsigned short* blp = wl + (kkc + ks) * 8192 + bofs;
      #pragma unroll
      for (int nf = 0; nf < 4; nf++) {
        b_h[nf][ks] = *(const short8*)(bhp + nf * 512);
        b_l[nf][ks] = *(const short8*)(blp + nf * 512);
      }
    }
    // advance indices; prefetch next A buffer (cc2 wraps at 4: 4 x 64ci = 256ci)
    cc2++; if (cc2 == 4) { cc2 = 0; kxc++; if (kxc == 9) { kxc = 0; kyc++; } }
    if (s < 107) {
      stageA((s + 1) % 3, (kyc * 20 + kxc) * 256, cc2 * 64);
      asm volatile("s_waitcnt vmcnt(20)" ::: "memory");  // A(s) landed; B(s)+A(s+1) in flight
    } else {
      asm volatile("s_waitcnt vmcnt(16)" ::: "memory");  // A(s) landed; B(s) in flight
    }
    asm volatile("s_barrier" ::: "memory");

    char* base = lds + (s % 3) * 16384;
    #pragma unroll
    for (int ks = 0; ks < 2; ks++) {
      short8 a_h[4], a_l[4];
      #pragma unroll
      for (int mf = 0; mf < 4; mf++) {
        const int row = mf * 16 + l15;
        const int off = ((row * 8 + ks * 4 + l4) ^ (l15 & 7)) << 4;
        a_h[mf] = *(const short8*)(base + off);
        a_l[mf] = *(const short8*)(base + 8192 + off);
      }
      __builtin_amdgcn_s_setprio(1);
      #pragma unroll
      for (int nf = 0; nf < 4; nf++)
        #pragma unroll
        for (int mf = 0; mf < 4; mf++) {
          f32x4 a = acc[mf][nf];
          a = __builtin_amdgcn_mfma_f32_16x16x32_bf16(a_h[mf], b_h[nf][ks], a, 0, 0, 0);
          a = __builtin_amdgcn_mfma_f32_16x16x32_bf16(a_l[mf], b_h[nf][ks], a, 0, 0, 0);
          a = __builtin_amdgcn_mfma_f32_16x16x32_bf16(a_h[mf], b_l[nf][ks], a, 0, 0, 0);
          acc[mf][nf] = a;
        }
      __builtin_amdgcn_s_setprio(0);
    }
  }

  // epilogue: C[pix][co]; 16x16 C/D: col=lane&15, row=(lane>>4)*4+reg
  float* pout = part + kg * 2359296;
  #pragma unroll
  for (int mf = 0; mf < 4; mf++)
    #pragma unroll
    for (int nf = 0; nf < 4; nf++) {
      const int co = w * 64 + nf * 16 + l15;
      #pragma unroll
      for (int reg = 0; reg < 4; reg++) {
        const int pix = m0 + mf * 16 + l4 * 4 + reg;
        const int b  = pix / 36;
        const int sp = pix - b * 36;
        pout[b * 9216 + co * 36 + sp] = acc[mf][nf][reg];
      }
    }
}

// ======== combine 3 split-K partials + bias, squash(8); emit u_T only =======
__global__ void combine_squash(const float* __restrict__ part,
                               const float* __restrict__ pb,
                               float* __restrict__ uT)
{
  const int id = blockIdx.x * 256 + threadIdx.x;  // 0..294911
  const int b = id / 1152;
  const int r = id % 1152;
  const float* p0 = part + b * 9216 + r * 8;
  float v[8];
  #pragma unroll
  for (int i = 0; i < 8; i++) v[i] = p0[i] + p0[2359296 + i] + p0[4718592 + i];
  #pragma unroll
  for (int i = 0; i < 8; i++) v[i] += pb[(r * 8 + i) / 36];
  float sq = 0.f;
  #pragma unroll
  for (int i = 0; i < 8; i++) sq += v[i] * v[i];
  float scale = sq / ((1.f + sq) * sqrtf(sq));
  #pragma unroll
  for (int i = 0; i < 8; i++) uT[(r * 256 + b) * 8 + i] = v[i] * scale;
}

// ===== s partials: grid 640 = 10 c x 64 r-chunks(18); block 256 (thread=b) ==
__global__ __launch_bounds__(256) void s_pass(
    const float* __restrict__ uT, const float* __restrict__ Wdc,
    const float* __restrict__ bij, float* __restrict__ spart, int uniform)
{
  const int c  = blockIdx.x % 10;
  const int q  = blockIdx.x / 10;          // 0..63
  const int r0 = q * 18;
  const int t  = threadIdx.x;
  __shared__ float wsm[18 * 128];          // 9216 B
  __shared__ float cw[18];
  __shared__ float red[8];

  #pragma unroll
  for (int k = 0; k < 9; k++) {
    int idx = t + k * 256;                 // < 2304
    int r = idx >> 7, i = idx & 127;
    wsm[idx] = Wdc[((r0 + r) * 10 + c) * 128 + i];
  }
  if (uniform) {
    if (t < 18) cw[t] = 1.f / 1152.f;
  } else {
    float bv[5]; float m = -1e30f;
    #pragma unroll
    for (int rr = 0; rr < 5; rr++) {
      int r = t + rr * 256;
      bv[rr] = (r < 1152) ? bij[c * 1152 + r] : -1e30f;
      m = fmaxf(m, bv[rr]);
    }
    #pragma unroll
    for (int off = 32; off; off >>= 1) m = fmaxf(m, __shfl_down(m, off, 64));
    if ((t & 63) == 0) red[t >> 6] = m;
    __syncthreads();
    m = fmaxf(fmaxf(red[0], red[1]), fmaxf(red[2], red[3]));
    float ssum = 0.f;
    #pragma unroll
    for (int rr = 0; rr < 5; rr++)
      ssum += (t + rr * 256 < 1152) ? expf(bv[rr] - m) : 0.f;
    #pragma unroll
    for (int off = 32; off; off >>= 1) ssum += __shfl_down(ssum, off, 64);
    if ((t & 63) == 0) red[4 + (t >> 6)] = ssum;
    __syncthreads();
    float inv = 1.f / (red[4] + red[5] + red[6] + red[7]);
    if (t < 18) cw[t] = expf(bij[c * 1152 + r0 + t] - m) * inv;
  }
  __syncthreads();

  const float4* up = (const float4*)(uT + (r0 * 256 + t) * 8);
  float acc[16];
  #pragma unroll
  for (int o = 0; o < 16; o++) acc[o] = 0.f;
  #pragma unroll 1
  for (int r = 0; r < 18; r++) {
    float4 x0 = up[r * 512], x1 = up[r * 512 + 1];
    float cwr = cw[r];
    const float* wr = &wsm[r * 128];
    #pragma unroll
    for (int o = 0; o < 16; o++) {
      const float4 wa = *(const float4*)(wr + o * 8);
      const float4 wb = *(const float4*)(wr + o * 8 + 4);
      acc[o] += cwr * (wa.x*x0.x + wa.y*x0.y + wa.z*x0.z + wa.w*x0.w
                     + wb.x*x1.x + wb.y*x1.y + wb.z*x1.z + wb.w*x1.w);
    }
  }
  float* op = spart + q * 40960 + (t * 10 + c) * 16;
  #pragma unroll
  for (int o = 0; o < 16; o++) op[o] = acc[o];
}

// ===== fused: sum 64 r-chunk partials; non-final: squash -> vT; final: sbuf =
template <int FINAL>
__global__ void reduce_squash(const float* __restrict__ spart, float* __restrict__ outb)
{
  const int id = blockIdx.x * 256 + threadIdx.x;   // < 40960; id=(b*10+c)*16+o
  float a = 0.f;
  #pragma unroll 8
  for (int q = 0; q < 64; q++) a += spart[q * 40960 + id];
  if (FINAL) { outb[id] = a; return; }
  float sq = a * a;
  #pragma unroll
  for (int off = 8; off; off >>= 1) sq += __shfl_xor(sq, off, 16);
  float scale = sq / ((1.f + sq) * sqrtf(sq));
  const int bc = id >> 4, o = id & 15;
  const int b = bc / 10, c = bc - b * 10;
  outb[(c * 256 + b) * 16 + o] = a * scale;
}

// == a[r,c] = (1/B) sum_{b,o} dot(W[r,c,o],u[b,r]) * v[b,c,o]; bij (+)= a ====
__global__ __launch_bounds__(256) void a_pass(
    const float* __restrict__ uT, const float* __restrict__ W,
    const float* __restrict__ vT, float* __restrict__ bij, int assign)
{
  const int r = blockIdx.x;
  const int t = threadIdx.x;
  __shared__ float wsl[1280];
  __shared__ float lred[4][10];
  for (int i = t; i < 1280; i += 256) wsl[i] = W[r * 1280 + i];
  __syncthreads();
  const float4* up = (const float4*)(uT + (r * 256 + t) * 8);
  float4 ua = up[0], ub = up[1];
  const int lane = t & 63, wid = t >> 6;
  #pragma unroll 1
  for (int c = 0; c < 10; c++) {
    const float* wc = &wsl[c * 128];
    const float4* vp = (const float4*)(vT + (c * 256 + t) * 16);
    float p = 0.f;
    #pragma unroll
    for (int q = 0; q < 4; q++) {
      float4 vq = vp[q];
      p += dot8(wc + (q * 4 + 0) * 8, ua, ub) * vq.x;
      p += dot8(wc + (q * 4 + 1) * 8, ua, ub) * vq.y;
      p += dot8(wc + (q * 4 + 2) * 8, ua, ub) * vq.z;
      p += dot8(wc + (q * 4 + 3) * 8, ua, ub) * vq.w;
    }
    for (int off = 32; off; off >>= 1) p += __shfl_down(p, off, 64);
    if (lane == 0) lred[wid][c] = p;
  }
  __syncthreads();
  if (t < 10) {
    float a = (lred[0][t] + lred[1][t] + lred[2][t] + lred[3][t]) * (1.f / 256.f);
    float o = assign ? 0.f : bij[t * 1152 + r];
    bij[t * 1152 + r] = o + a;
  }
}

// == finalize: squash(final) -> outp; batch softmax; argmax mask; t vector ===
__global__ __launch_bounds__(256) void finalize(
    const float* __restrict__ sbuf, float* __restrict__ outp,
    float* __restrict__ maskedo, float* __restrict__ tbuf)
{
  const int b = threadIdx.x;
  __shared__ float nsm[256][10];
  __shared__ float red[8];
  #pragma unroll 1
  for (int c = 0; c < 10; c++) {
    const float4* sp = (const float4*)(sbuf + (b * 10 + c) * 16);
    float4 q0 = sp[0], q1 = sp[1], q2 = sp[2], q3 = sp[3];
    float sq = q0.x*q0.x+q0.y*q0.y+q0.z*q0.z+q0.w*q0.w
             + q1.x*q1.x+q1.y*q1.y+q1.z*q1.z+q1.w*q1.w
             + q2.x*q2.x+q2.y*q2.y+q2.z*q2.z+q2.w*q2.w
             + q3.x*q3.x+q3.y*q3.y+q3.z*q3.z+q3.w*q3.w;
    float scale = sq / ((1.f + sq) * sqrtf(sq));
    float4* op = (float4*)(outp + (b * 10 + c) * 16);
    op[0] = make_float4(q0.x*scale, q0.y*scale, q0.z*scale, q0.w*scale);
    op[1] = make_float4(q1.x*scale, q1.y*scale, q1.z*scale, q1.w*scale);
    op[2] = make_float4(q2.x*scale, q2.y*scale, q2.z*scale, q2.w*scale);
    op[3] = make_float4(q3.x*scale, q3.y*scale, q3.z*scale, q3.w*scale);
    nsm[b][c] = sq / (1.f + sq);          // = ||squash(s)||
  }
  __syncthreads();
  float sc[10];
  #pragma unroll
  for (int c = 0; c < 10; c++) {
    float x = nsm[b][c];
    float m = x;
    #pragma unroll
    for (int off = 32; off; off >>= 1) m = fmaxf(m, __shfl_down(m, off, 64));
    if ((b & 63) == 0) red[b >> 6] = m;
    __syncthreads();
    m = fmaxf(fmaxf(red[0], red[1]), fmaxf(red[2], red[3]));
    float e = expf(x - m), ss = e;
    #pragma unroll
    for (int off = 32; off; off >>= 1) ss += __shfl_down(ss, off, 64);
    if ((b & 63) == 0) red[4 + (b >> 6)] = ss;
    __syncthreads();
    sc[c] = e / (red[4] + red[5] + red[6] + red[7]);
    __syncthreads();
  }
  int idx = 0; float best = sc[0];
  #pragma unroll
  for (int c = 1; c < 10; c++) if (sc[c] > best) { best = sc[c]; idx = c; }
  #pragma unroll
  for (int c = 0; c < 10; c++) {
    float msk = (c == idx) ? 1.f : 0.f;
    maskedo[b * 10 + c] = msk;
    const float4* op = (const float4*)(outp + (b * 10 + c) * 16);
    float4* tp = (float4*)(tbuf + b * 160 + c * 16);
    #pragma unroll
    for (int qq = 0; qq < 4; qq++) {
      float4 vv = op[qq];
      tp[qq] = make_float4(vv.x * msk, vv.y * msk, vv.z * msk, vv.w * msk);
    }
  }
}

// ==================== small GEMM: C = act(A[M,K] @ B[K,N] + bias) ===========
template <int ACT>
__global__ __launch_bounds__(256) void gemm_act(
    const float* __restrict__ A, const float* __restrict__ B,
    const float* __restrict__ bias, float* __restrict__ C, int M, int N, int K)
{
  __shared__ float As[64][17];
  __shared__ float Bs[16][64];
  const int t = threadIdx.x;
  const int tx = t & 15, ty = t >> 4;
  const int m0 = blockIdx.y * 64, n0 = blockIdx.x * 64;
  float acc[4][4] = {};
  for (int kb = 0; kb < K; kb += 16) {
    {
      int row = t >> 2, c4 = (t & 3) * 4;
      float4 av = *(const float4*)(A + (m0 + row) * K + kb + c4);
      As[row][c4+0]=av.x; As[row][c4+1]=av.y; As[row][c4+2]=av.z; As[row][c4+3]=av.w;
    }
    {
      int row = t >> 4, c4 = (t & 15) * 4;
      float4 bv = make_float4(0.f, 0.f, 0.f, 0.f);
      if (n0 + c4 < N) bv = *(const float4*)(B + (kb + row) * N + n0 + c4);
      Bs[row][c4+0]=bv.x; Bs[row][c4+1]=bv.y; Bs[row][c4+2]=bv.z; Bs[row][c4+3]=bv.w;
    }
    __syncthreads();
    #pragma unroll
    for (int kk = 0; kk < 16; kk++) {
      float a_[4], b_[4];
      #pragma unroll
      for (int i = 0; i < 4; i++) a_[i] = As[ty * 4 + i][kk];
      #pragma unroll
      for (int j = 0; j < 4; j++) b_[j] = Bs[kk][tx * 4 + j];
      #pragma unroll
      for (int i = 0; i < 4; i++)
        for (int j = 0; j < 4; j++)
          acc[i][j] = fmaf(a_[i], b_[j], acc[i][j]);
    }
    __syncthreads();
  }
  #pragma unroll
  for (int i = 0; i < 4; i++) {
    int row = m0 + ty * 4 + i;
    #pragma unroll
    for (int j = 0; j < 4; j++) {
      int col = n0 + tx * 4 + j;
      if (col < N) {
        float val = acc[i][j] + bias[col];
        if (ACT == 0) val = val > 0.f ? val : 0.f;
        else          val = 1.f / (1.f + expf(-val));
        C[row * N + col] = val;
      }
    }
  }
}

// ===========================================================================
extern "C" void kernel_launch(void* const* d_in, const int* in_sizes, int n_in,
                              void* d_out, int out_size, void* d_ws, size_t ws_size,
                              hipStream_t stream)
{
  const float* data = (const float*)d_in[0];
  const float* w1   = (const float*)d_in[1];
  const float* b1   = (const float*)d_in[2];
  const float* pw   = (const float*)d_in[3];
  const float* pb   = (const float*)d_in[4];
  const float* Wdc  = (const float*)d_in[5];
  const float* dw1  = (const float*)d_in[6];
  const float* db1  = (const float*)d_in[7];
  const float* dw2  = (const float*)d_in[8];
  const float* db2  = (const float*)d_in[9];
  const float* dw3  = (const float*)d_in[10];
  const float* db3  = (const float*)d_in[11];

  float* out     = (float*)d_out;
  float* outp    = out;              // [256][10][16][1]
  float* recon   = out + 40960;      // [256][784]
  float* maskedo = out + 241664;     // [256][10]

  char* wsb = (char*)d_ws;
  // big section (conv phase)
  unsigned short* x1h = (unsigned short*)(wsb);               // 52,428,800 B
  unsigned short* x1l = (unsigned short*)(wsb + 52428800);    // 52,428,800
  unsigned short* wbh = (unsigned short*)(wsb + 104857600);   // 10,616,832
  unsigned short* wbl = (unsigned short*)(wsb + 115474432);   // 10,616,832
  float*  part = (float*)(wsb + 126091264);                   // 28,311,552 (3 partials)
  unsigned short* w1th = (unsigned short*)(wsb + 154402816);  //     49,152
  unsigned short* w1tl = (unsigned short*)(wsb + 154451968);  //     49,152
  // overlay section (x1h region is dead after conv2)
  float* uT   = (float*)(wsb);                                //  9,437,184
  float* vT   = (float*)(wsb + 9437184);                      //    163,840
  float* bij  = (float*)(wsb + 9601024);                      //     46,080
  float* sbuf = (float*)(wsb + 9647104);                      //    163,840
  float* spart= (float*)(wsb + 9810944);                      // 10,485,760
  float* tbuf = (float*)(wsb + 20296704);                     //    163,840
  float* h1   = (float*)(wsb + 20460544);                     //    524,288
  float* h2   = (float*)(wsb + 20984832);                     //  1,048,576

  w1prep<<<96, 256, 0, stream>>>(w1, w1th, w1tl);
  conv1_mfma<<<512, 256, 0, stream>>>(data, w1th, w1tl, b1, x1h, x1l);
  wprep<<<256, 256, 0, stream>>>(pw, wbh, wbl);
  conv2_mfma<<<432, 256, 0, stream>>>(x1h, x1l, wbh, wbl, part);
  combine_squash<<<1152, 256, 0, stream>>>(part, pb, uT);

  // routing iteration 0 (b_ij = 0 -> uniform c); b_ij assigned, not added
  s_pass<<<640, 256, 0, stream>>>(uT, Wdc, bij, spart, 1);
  reduce_squash<0><<<160, 256, 0, stream>>>(spart, vT);
  a_pass<<<1152, 256, 0, stream>>>(uT, Wdc, vT, bij, 1);
  // iteration 1
  s_pass<<<640, 256, 0, stream>>>(uT, Wdc, bij, spart, 0);
  reduce_squash<0><<<160, 256, 0, stream>>>(spart, vT);
  a_pass<<<1152, 256, 0, stream>>>(uT, Wdc, vT, bij, 0);
  // iteration 2 (final) + fused decoder head
  s_pass<<<640, 256, 0, stream>>>(uT, Wdc, bij, spart, 0);
  reduce_squash<1><<<160, 256, 0, stream>>>(spart, sbuf);
  finalize<<<1, 256, 0, stream>>>(sbuf, outp, maskedo, tbuf);

  gemm_act<0><<<dim3(8, 4),  256, 0, stream>>>(tbuf, dw1, db1, h1,    256, 512,  160);
  gemm_act<0><<<dim3(16, 4), 256, 0, stream>>>(h1,   dw2, db2, h2,    256, 1024, 512);
  gemm_act<1><<<dim3(13, 4), 256, 0, stream>>>(h2,   dw3, db3, recon, 256, 784,  1024);
}